// Round 11
// baseline (664.635 us; speedup 1.0000x reference)
//
#include <hip/hip_runtime.h>

// Spiking self-attention block (spikformer SSA), MI355X fp32 implementation.
// T=4 B=32 C=384 H=W=14 (N=196), heads=8, d=48.
//
// Exactness: LIF spikes are EXACTLY 0/1; attention is exact integer math.
// Conv GEMM: single fp32 accumulator per output, ascending K, fmaf per step
// (matched XLA bit-for-bit rounds 1-10). MFMA off the table (order change).
//
// R11: GEMM rebuilt around the MEASURED LDS-issue bound (8x8 tile: 48 LDS
// cyc vs 32 VALU cyc per wave-k -> VALUBusy capped ~70%, seen R3/R8/R9).
// New: 128-thr block, 128x128 tile, 16co x 8col per thread -> 6 b128/wave-k
// for 2x the MACs (LDS/VALU ~80/64). Register budget kept safe (~180):
// acc 128 + A-prefetch 16 only; B staged via global_load_lds width=16
// (no VGPR round-trip) into double-buffered LDS; loads for tile i+1 fly
// during compute(i) (~1800 cyc >> 900 cyc HBM) so barrier drain is free.
// qkv back to ONE fused z=3 dispatch (1764 blocks, ~97% fill; R10 showed
// 588-block dispatches are tail-quantized to ~76% fill).
// k_mask/k_attn/lif4: R8 verbatim.

#define T_ 4
#define B_ 32
#define C_ 384
#define N_ 196
#define NH_ 8
#define D_ 48
#define TB_ (T_ * B_)                 // 128
#define CN_ ((size_t)C_ * N_)         // 75264
#define BCN4_ (B_ * C_ * (N_ / 4))    // 602112 float4 units per (g,t)
#define TBCN_ ((size_t)T_ * B_ * C_ * N_)  // 9,633,792 floats
typedef unsigned long long u64;

// ---------------------------------------------------------------------------
// GEMM: Y[g][tb][co][n] = sum_c Wg[co][c] * X[tb][c][n]
// Cols flattened j = tb*196 + n; 25088 = 196 tiles of 128.
// Block: 128 thr (2 waves), tile 128co x 128col, 16x8 per thread.
// B: global_load_lds (16B/lane, wave covers 2 k-rows) into LDS dbuf.
// A: VGPR prefetch one tile ahead, ds_write scatter (transpose), LDS dbuf.
// grid: x = col-tile (196), y = co-tile (3), z = g (or 1 for wp).
// ---------------------------------------------------------------------------
__global__ __launch_bounds__(128) void gemm_f32(
    const float* __restrict__ X, const float* __restrict__ W0,
    const float* __restrict__ W1, const float* __restrict__ W2,
    float* __restrict__ P)
{
  const int g = blockIdx.z;
  const float* __restrict__ W = (g == 0) ? W0 : (g == 1) ? W1 : W2;
  const int co0 = blockIdx.y * 128;
  const int j0 = blockIdx.x * 128;
  __shared__ float As[2][16][128];   // 16 KB
  __shared__ float Bs[2][16][128];   // 16 KB
  const int tid = threadIdx.x;
  const int tx = tid & 15, ty = tid >> 4;
  const int wv = tid >> 6, lane = tid & 63;

  // A staging: thread owns W row co0+tid, 16 floats per c-tile.
  const float* wrow = W + (size_t)(co0 + tid) * C_;
  // B source per lane: col quad jcol, k-row pair selector krow.
  const int jcol = j0 + (lane & 31) * 4;
  const int tbB = jcol / N_;
  const float* xB = X + (size_t)tbB * CN_ + (jcol - tbB * N_);
  const int krow = lane >> 5;   // 0/1: second half-wave loads row kb+1

  // ---- prologue: stage tile 0, prefetch A tile 1 ----
  float4 a0 = *(const float4*)(wrow + 0);
  float4 a1 = *(const float4*)(wrow + 4);
  float4 a2 = *(const float4*)(wrow + 8);
  float4 a3 = *(const float4*)(wrow + 12);
#pragma unroll
  for (int q = 0; q < 4; ++q) {
    const int kb = q * 4 + wv * 2;
    const float* src = xB + (size_t)(kb + krow) * N_;
    __builtin_amdgcn_global_load_lds(
        (const __attribute__((address_space(1))) void*)src,
        (__attribute__((address_space(3))) void*)&Bs[0][kb][0], 16, 0, 0);
  }
  float4 n0 = *(const float4*)(wrow + 16);
  float4 n1 = *(const float4*)(wrow + 20);
  float4 n2 = *(const float4*)(wrow + 24);
  float4 n3 = *(const float4*)(wrow + 28);
  As[0][0][tid] = a0.x;  As[0][1][tid] = a0.y;  As[0][2][tid] = a0.z;  As[0][3][tid] = a0.w;
  As[0][4][tid] = a1.x;  As[0][5][tid] = a1.y;  As[0][6][tid] = a1.z;  As[0][7][tid] = a1.w;
  As[0][8][tid] = a2.x;  As[0][9][tid] = a2.y;  As[0][10][tid] = a2.z; As[0][11][tid] = a2.w;
  As[0][12][tid] = a3.x; As[0][13][tid] = a3.y; As[0][14][tid] = a3.z; As[0][15][tid] = a3.w;
  __syncthreads();

  float acc[16][8] = {};
  for (int i = 0; i < 24; ++i) {     // 384 / 16 c-tiles, ascending
    const int cur = i & 1, nxt = cur ^ 1;
    if (i < 23) {
      const int cb = (i + 1) * 16;
      // B tile i+1 -> Bs[nxt] (in flight across the whole compute below)
#pragma unroll
      for (int q = 0; q < 4; ++q) {
        const int kb = q * 4 + wv * 2;
        const float* src = xB + (size_t)(cb + kb + krow) * N_;
        __builtin_amdgcn_global_load_lds(
            (const __attribute__((address_space(1))) void*)src,
            (__attribute__((address_space(3))) void*)&Bs[nxt][kb][0], 16, 0, 0);
      }
      // A tile i+1 from regs prefetched one iteration ago
      As[nxt][0][tid] = n0.x;  As[nxt][1][tid] = n0.y;  As[nxt][2][tid] = n0.z;  As[nxt][3][tid] = n0.w;
      As[nxt][4][tid] = n1.x;  As[nxt][5][tid] = n1.y;  As[nxt][6][tid] = n1.z;  As[nxt][7][tid] = n1.w;
      As[nxt][8][tid] = n2.x;  As[nxt][9][tid] = n2.y;  As[nxt][10][tid] = n2.z; As[nxt][11][tid] = n2.w;
      As[nxt][12][tid] = n3.x; As[nxt][13][tid] = n3.y; As[nxt][14][tid] = n3.z; As[nxt][15][tid] = n3.w;
      if (i < 22) {
        const float* wn = wrow + (i + 2) * 16;
        n0 = *(const float4*)(wn + 0);
        n1 = *(const float4*)(wn + 4);
        n2 = *(const float4*)(wn + 8);
        n3 = *(const float4*)(wn + 12);
      }
    }
#pragma unroll
    for (int k = 0; k < 16; ++k) {
      float a[16], b[8];
#pragma unroll
      for (int q = 0; q < 4; ++q)
        *(float4*)&a[q * 4] = *(const float4*)&As[cur][k][ty * 16 + q * 4];
      *(float4*)&b[0] = *(const float4*)&Bs[cur][k][tx * 4];
      *(float4*)&b[4] = *(const float4*)&Bs[cur][k][64 + tx * 4];
#pragma unroll
      for (int r = 0; r < 16; ++r)
#pragma unroll
        for (int c = 0; c < 8; ++c)
          acc[r][c] = fmaf(a[r], b[c], acc[r][c]);
    }
    __syncthreads();
  }
  // Epilogue: two float4 quads per row (quads never straddle tb; 196%4==0).
  {
    const int jA = j0 + tx * 4;
    const int jB = j0 + 64 + tx * 4;
    const int tbA = jA / N_, tbB2 = jB / N_;
    float* pA = P + (size_t)(g * TB_ + tbA) * CN_ + (jA - tbA * N_);
    float* pB = P + (size_t)(g * TB_ + tbB2) * CN_ + (jB - tbB2 * N_);
#pragma unroll
    for (int r = 0; r < 16; ++r) {
      const size_t ro = (size_t)(co0 + ty * 16 + r) * N_;
      *(float4*)&pA[ro] = make_float4(acc[r][0], acc[r][1], acc[r][2], acc[r][3]);
      *(float4*)&pB[ro] = make_float4(acc[r][4], acc[r][5], acc[r][6], acc[r][7]);
    }
  }
}

// ---------------------------------------------------------------------------
// Multi-step LIF over t with folded BN (final conv only).
// ---------------------------------------------------------------------------
__global__ __launch_bounds__(256) void lif4(
    const float* __restrict__ In, float* __restrict__ Out,
    const float* __restrict__ s0, const float* __restrict__ b0, float vth)
{
  const long u = (long)blockIdx.x * 256 + threadIdx.x;
  if (u >= BCN4_) return;
  const long r = u;
  const int c = (int)((r / (N_ / 4)) % C_);
  const bool has_bn = (s0 != nullptr);
  const float sc = has_bn ? s0[c] : 1.0f;
  const float bi = has_bn ? b0[c] : 0.0f;
  const float4* In4 = (const float4*)In;
  float4* Out4 = (float4*)Out;
  float v[4] = {0.f, 0.f, 0.f, 0.f};
#pragma unroll
  for (int t = 0; t < T_; ++t) {
    const long idx = (long)t * BCN4_ + r;
    const float4 y4 = In4[idx];
    float y[4] = {y4.x, y4.y, y4.z, y4.w};
    float o[4];
#pragma unroll
    for (int e = 0; e < 4; ++e) {
      const float yb = has_bn ? __fadd_rn(__fmul_rn(y[e], sc), bi) : y[e];
      v[e] = __fadd_rn(v[e], __fmul_rn(__fsub_rn(yb, v[e]), 0.5f));
      const bool fire = (v[e] >= vth);
      o[e] = fire ? 1.0f : 0.0f;
      v[e] = fire ? 0.0f : v[e];
    }
    Out4[idx] = make_float4(o[0], o[1], o[2], o[3]);
  }
}

// ---------------------------------------------------------------------------
// k_mask (R8): conv-LIF -> spike bitmasks. Wave-task = (g,h,b,j): 16 loads
// in flight, LIF recurrence, 16 ballots, lane0 stores 16 u64.
// MSK layout: [(h*32+b)][g][t][j][w]  (2304 u64 per (h,b)).
// ---------------------------------------------------------------------------
__global__ __launch_bounds__(256) void k_mask(
    const float* __restrict__ P, u64* __restrict__ MSK,
    const float* __restrict__ sq, const float* __restrict__ bq,
    const float* __restrict__ sk, const float* __restrict__ bk,
    const float* __restrict__ sv, const float* __restrict__ bv)
{
  const int wave = threadIdx.x >> 6, lane = threadIdx.x & 63;
  const int task = blockIdx.x * 4 + wave;      // 0..36863
  const int j = task % D_;
  int r = task / D_;
  const int b = r & 31; r >>= 5;
  const int h = r & 7;  r >>= 3;
  const int g = r;                              // 0..2
  const int c = h * D_ + j;
  const float sc = (g == 0 ? sq : g == 1 ? sk : sv)[c];
  const float bi = (g == 0 ? bq : g == 1 ? bk : bv)[c];
  const float* base = P + (size_t)g * TB_ * CN_ + (size_t)b * CN_ + (size_t)c * N_;

  float y[4][T_];
  bool act[4];
#pragma unroll
  for (int w = 0; w < 4; ++w) {
    const int m = w * 64 + lane;
    act[w] = (m < N_);
    const int mc = act[w] ? m : (N_ - 1);
#pragma unroll
    for (int t = 0; t < T_; ++t)
      y[w][t] = base[(size_t)t * B_ * CN_ + mc];   // 16 independent loads
  }
  u64* mb = MSK + ((size_t)(h * 32 + b) * 3 + g) * (T_ * D_ * 4) + j * 4;
  float v[4] = {0.f, 0.f, 0.f, 0.f};
#pragma unroll
  for (int t = 0; t < T_; ++t) {
#pragma unroll
    for (int w = 0; w < 4; ++w) {
      const float yb = __fadd_rn(__fmul_rn(y[w][t], sc), bi);
      v[w] = __fadd_rn(v[w], __fmul_rn(__fsub_rn(yb, v[w]), 0.5f));
      const bool fire = (v[w] >= 1.0f);
      if (fire) v[w] = 0.f;
      const u64 bl = __ballot(fire && act[w]);
      if (lane == 0) mb[(size_t)t * (D_ * 4) + w] = bl;
    }
  }
}

// ---------------------------------------------------------------------------
// k_attn (R8): per (h,b): masks to LDS, build qT + G bit-planes, apply
// out = sum_p 2^p popcount(qT & Gp[p][d]), attn-LIF, write binary spikes.
// ---------------------------------------------------------------------------
__global__ __launch_bounds__(1024) void k_attn(
    const u64* __restrict__ MSK, float* __restrict__ O)
{
  const int h = blockIdx.x;   // 8
  const int b = blockIdx.y;   // 32
  __shared__ u64 msk[3][T_][D_][4];   // 18432 B
  __shared__ u64 qT[T_][208];         // 6656 B
  __shared__ u64 Gp[T_][8][D_];       // 12288 B
  const int tid = threadIdx.x;
  const int wave = tid >> 6, lane = tid & 63;

  {
    const u64* ms = MSK + (size_t)(h * 32 + b) * 2304;
    u64* mf = &msk[0][0][0][0];
    for (int off = tid; off < 2304; off += 1024) mf[off] = ms[off];
  }
  __syncthreads();

  // qT[t][n] = q bits over j
  {
    const int t = wave >> 2, w = wave & 3;
    const int n = w * 64 + lane;
    u64 qr = 0ull;
#pragma unroll 8
    for (int j = 0; j < D_; ++j)
      qr |= ((msk[0][t][j][w] >> lane) & 1ull) << j;
    if (n < N_) qT[t][n] = qr;
  }
  // Gp[t][p][d]: bit-planes of G[j][d] = popcount_m(k_j & v_d), lanes=j
  for (int task = wave; task < T_ * D_; task += 16) {
    const int t = task / D_, d = task - (task / D_) * D_;
    const bool ja = (lane < D_);
    const int j = ja ? lane : (D_ - 1);
    const u64* kj = msk[1][t][j];
    const u64* vd = msk[2][t][d];
    const int gi = __popcll(kj[0] & vd[0]) + __popcll(kj[1] & vd[1]) +
                   __popcll(kj[2] & vd[2]) + __popcll(kj[3] & vd[3]);
#pragma unroll
    for (int p = 0; p < 8; ++p) {
      const u64 bl = __ballot(ja && ((gi >> p) & 1));
      if (lane == 0) Gp[t][p][d] = bl;
    }
  }
  __syncthreads();

  const int u = tid;
  if (u < 4 * N_) {
    const int dq = u / N_;
    const int n = u - dq * N_;
    const int d0 = dq * 12;
    float vmem[12];
#pragma unroll
    for (int i = 0; i < 12; ++i) vmem[i] = 0.f;
    for (int t = 0; t < T_; ++t) {
      const u64 qr = qT[t][n];
      float* ob = O + ((size_t)(t * B_ + b) * C_ + h * D_ + d0) * N_ + n;
#pragma unroll
      for (int i = 0; i < 12; ++i) {
        int acc = 0;
#pragma unroll
        for (int p = 0; p < 8; ++p)
          acc += __popcll(qr & Gp[t][p][d0 + i]) << p;
        const float y = __int2float_rn(acc) * 0.125f;  // exact
        vmem[i] = __fadd_rn(vmem[i], __fmul_rn(__fsub_rn(y, vmem[i]), 0.5f));
        const bool fire = (vmem[i] >= 0.5f);
        ob[(size_t)i * N_] = fire ? 1.0f : 0.0f;
        if (fire) vmem[i] = 0.f;
      }
    }
  }
}

// ---------------------------------------------------------------------------
extern "C" void kernel_launch(void* const* d_in, const int* in_sizes, int n_in,
                              void* d_out, int out_size, void* d_ws, size_t ws_size,
                              hipStream_t stream) {
  const float* x  = (const float*)d_in[0];
  const float* wq = (const float*)d_in[1];
  const float* sq = (const float*)d_in[2];
  const float* bq = (const float*)d_in[3];
  const float* wk = (const float*)d_in[4];
  const float* sk = (const float*)d_in[5];
  const float* bk = (const float*)d_in[6];
  const float* wv = (const float*)d_in[7];
  const float* sv = (const float*)d_in[8];
  const float* bv = (const float*)d_in[9];
  const float* wp = (const float*)d_in[10];
  const float* sp = (const float*)d_in[11];
  const float* bp = (const float*)d_in[12];
  float* out = (float*)d_out;

  float* P = (float*)d_ws;              // 3*TBCN qkv preacts
  float* O = P + 3 * TBCN_;             // TBCN attn spikes
  u64* MSK = (u64*)(P + 4 * TBCN_);     // 256 * 2304 u64 = 4.7 MB
  float* P2 = P;                        // final conv preact reuses q region

  gemm_f32<<<dim3(196, 3, 3), 128, 0, stream>>>(x, wq, wk, wv, P);
  k_mask<<<dim3(9216), 256, 0, stream>>>(P, MSK, sq, bq, sk, bk, sv, bv);
  k_attn<<<dim3(NH_, B_), 1024, 0, stream>>>(MSK, O);
  gemm_f32<<<dim3(196, 3, 1), 128, 0, stream>>>(O, wp, wp, wp, P2);
  lif4<<<dim3((BCN4_ + 255) / 256), 256, 0, stream>>>(P2, out, sp, bp, 1.0f);
}

// Round 12
// 589.320 us; speedup vs baseline: 1.1278x; 1.1278x over previous
//
#include <hip/hip_runtime.h>

// Spiking self-attention block (spikformer SSA), MI355X fp32 implementation.
// T=4 B=32 C=384 H=W=14 (N=196), heads=8, d=48.
//
// Exactness: LIF spikes are EXACTLY 0/1; attention is exact integer math.
// Conv GEMM: single fp32 accumulator per output, ascending K, fmaf per step
// (matched XLA bit-for-bit rounds 1-11). MFMA off the table (order change).
//
// R12: base = R8/R9 proven kernels. Two targeted changes:
// (a) GEMM BK=32: 12 barriers instead of 24 (R9's 28% stall is barrier/
//     drain); same ascending-c fmaf chain -> bit-exact. LDS 32KB/block,
//     still 2 blocks/CU at (256,2). Prefetch regs 32 floats -> VGPR ~120.
//     (R6/R7/R11 all died via occupancy/register collapse, not LDS math:
//     (256,4)/(768,3) caps and 128-thr dbuf. This keeps the proven shape.)
// (b) k_attn Phase B: Gp reads as wave-uniform ulonglong2 (b128) -> 48
//     LDS issues/t instead of 96; acc[12] per-p accumulation; stores
//     unchanged (coalesced).

#define T_ 4
#define B_ 32
#define C_ 384
#define N_ 196
#define NH_ 8
#define D_ 48
#define TB_ (T_ * B_)                 // 128
#define CN_ ((size_t)C_ * N_)         // 75264
#define BCN4_ (B_ * C_ * (N_ / 4))    // 602112 float4 units per (g,t)
#define TBCN_ ((size_t)T_ * B_ * C_ * N_)  // 9,633,792 floats
typedef unsigned long long u64;

// ---------------------------------------------------------------------------
// GEMM: Y[g][tb][co][n] = sum_c Wg[co][c] * X[tb][c][n]
// Cols flattened j = tb*196 + n; 25088 = 196 tiles of 128 (exact).
// Block: 128co x 128col, 256 thr, 8x8/thread (two stride-64 quads).
// BK=32 double-rate staging + register prefetch. grid (196, 3, g).
// ---------------------------------------------------------------------------
__global__ __launch_bounds__(256, 2) void gemm_f32(
    const float* __restrict__ X, const float* __restrict__ W0,
    const float* __restrict__ W1, const float* __restrict__ W2,
    float* __restrict__ P)
{
  const int g = blockIdx.z;
  const float* __restrict__ W = (g == 0) ? W0 : (g == 1) ? W1 : W2;
  const int co0 = blockIdx.y * 128;
  const int j0 = blockIdx.x * 128;
  __shared__ float As[32][128];   // 16 KB
  __shared__ float Bs[32][128];   // 16 KB
  const int tid = threadIdx.x;
  const int tx = tid & 15, ty = tid >> 4;

  // B staging: col quad bcol, k rows bk + {0,8,16,24}
  const int bcol = (tid & 31) * 4;
  const int bk = tid >> 5;
  const int bj = j0 + bcol;
  const int btb = bj / N_;
  const float* xb = X + (size_t)btb * CN_ + (bj - btb * N_);
  // A staging: row arow, 16 consecutive c at ac16
  const int arow = tid >> 1;
  const int ac16 = (tid & 1) * 16;
  const float* wrow0 = W + (size_t)(co0 + arow) * C_ + ac16;

  // Prefetch tile 0.
  float4 pa[4], pb[4];
#pragma unroll
  for (int q = 0; q < 4; ++q) {
    pa[q] = *(const float4*)(wrow0 + q * 4);
    pb[q] = *(const float4*)(xb + (size_t)(bk + 8 * q) * N_);
  }

  float acc[8][8] = {};
  for (int c0 = 0; c0 < C_; c0 += 32) {
    __syncthreads();   // prev-iter readers done (no-op first iter)
#pragma unroll
    for (int q = 0; q < 4; ++q) {
      As[ac16 + q * 4 + 0][arow] = pa[q].x;
      As[ac16 + q * 4 + 1][arow] = pa[q].y;
      As[ac16 + q * 4 + 2][arow] = pa[q].z;
      As[ac16 + q * 4 + 3][arow] = pa[q].w;
      *(float4*)&Bs[bk + 8 * q][bcol] = pb[q];
    }
    __syncthreads();
    if (c0 + 32 < C_) {  // prefetch next tile during compute below
#pragma unroll
      for (int q = 0; q < 4; ++q) {
        pa[q] = *(const float4*)(wrow0 + c0 + 32 + q * 4);
        pb[q] = *(const float4*)(xb + (size_t)(c0 + 32 + bk + 8 * q) * N_);
      }
    }
#pragma unroll
    for (int k = 0; k < 32; ++k) {
      float a[8], b[8];
      *(float4*)&a[0] = *(const float4*)&As[k][ty * 4];
      *(float4*)&a[4] = *(const float4*)&As[k][64 + ty * 4];
      *(float4*)&b[0] = *(const float4*)&Bs[k][tx * 4];
      *(float4*)&b[4] = *(const float4*)&Bs[k][64 + tx * 4];
#pragma unroll
      for (int i = 0; i < 8; ++i)
#pragma unroll
        for (int j = 0; j < 8; ++j)
          acc[i][j] = fmaf(a[i], b[j], acc[i][j]);
    }
  }
#pragma unroll
  for (int cg = 0; cg < 2; ++cg) {
    const int jj = j0 + cg * 64 + tx * 4;
    const int tb = jj / N_;
    float* pb2 = P + (size_t)(g * TB_ + tb) * CN_ + (jj - tb * N_);
#pragma unroll
    for (int rg = 0; rg < 2; ++rg) {
#pragma unroll
      for (int i = 0; i < 4; ++i) {
        const int r = rg * 4 + i;
        const int co = co0 + rg * 64 + ty * 4 + i;
        *(float4*)&pb2[(size_t)co * N_] = make_float4(
            acc[r][cg * 4 + 0], acc[r][cg * 4 + 1],
            acc[r][cg * 4 + 2], acc[r][cg * 4 + 3]);
      }
    }
  }
}

// ---------------------------------------------------------------------------
// Multi-step LIF over t with folded BN (final conv only).
// ---------------------------------------------------------------------------
__global__ __launch_bounds__(256) void lif4(
    const float* __restrict__ In, float* __restrict__ Out,
    const float* __restrict__ s0, const float* __restrict__ b0, float vth)
{
  const long u = (long)blockIdx.x * 256 + threadIdx.x;
  if (u >= BCN4_) return;
  const long r = u;
  const int c = (int)((r / (N_ / 4)) % C_);
  const bool has_bn = (s0 != nullptr);
  const float sc = has_bn ? s0[c] : 1.0f;
  const float bi = has_bn ? b0[c] : 0.0f;
  const float4* In4 = (const float4*)In;
  float4* Out4 = (float4*)Out;
  float v[4] = {0.f, 0.f, 0.f, 0.f};
#pragma unroll
  for (int t = 0; t < T_; ++t) {
    const long idx = (long)t * BCN4_ + r;
    const float4 y4 = In4[idx];
    float y[4] = {y4.x, y4.y, y4.z, y4.w};
    float o[4];
#pragma unroll
    for (int e = 0; e < 4; ++e) {
      const float yb = has_bn ? __fadd_rn(__fmul_rn(y[e], sc), bi) : y[e];
      v[e] = __fadd_rn(v[e], __fmul_rn(__fsub_rn(yb, v[e]), 0.5f));
      const bool fire = (v[e] >= vth);
      o[e] = fire ? 1.0f : 0.0f;
      v[e] = fire ? 0.0f : v[e];
    }
    Out4[idx] = make_float4(o[0], o[1], o[2], o[3]);
  }
}

// ---------------------------------------------------------------------------
// k_mask (R8): conv-LIF -> spike bitmasks. Wave-task = (g,h,b,j): 16 loads
// in flight, LIF recurrence, 16 ballots, lane0 stores 16 u64.
// MSK layout: [(h*32+b)][g][t][j][w]  (2304 u64 per (h,b)).
// ---------------------------------------------------------------------------
__global__ __launch_bounds__(256) void k_mask(
    const float* __restrict__ P, u64* __restrict__ MSK,
    const float* __restrict__ sq, const float* __restrict__ bq,
    const float* __restrict__ sk, const float* __restrict__ bk,
    const float* __restrict__ sv, const float* __restrict__ bv)
{
  const int wave = threadIdx.x >> 6, lane = threadIdx.x & 63;
  const int task = blockIdx.x * 4 + wave;      // 0..36863
  const int j = task % D_;
  int r = task / D_;
  const int b = r & 31; r >>= 5;
  const int h = r & 7;  r >>= 3;
  const int g = r;                              // 0..2
  const int c = h * D_ + j;
  const float sc = (g == 0 ? sq : g == 1 ? sk : sv)[c];
  const float bi = (g == 0 ? bq : g == 1 ? bk : bv)[c];
  const float* base = P + (size_t)g * TB_ * CN_ + (size_t)b * CN_ + (size_t)c * N_;

  float y[4][T_];
  bool act[4];
#pragma unroll
  for (int w = 0; w < 4; ++w) {
    const int m = w * 64 + lane;
    act[w] = (m < N_);
    const int mc = act[w] ? m : (N_ - 1);
#pragma unroll
    for (int t = 0; t < T_; ++t)
      y[w][t] = base[(size_t)t * B_ * CN_ + mc];   // 16 independent loads
  }
  u64* mb = MSK + ((size_t)(h * 32 + b) * 3 + g) * (T_ * D_ * 4) + j * 4;
  float v[4] = {0.f, 0.f, 0.f, 0.f};
#pragma unroll
  for (int t = 0; t < T_; ++t) {
#pragma unroll
    for (int w = 0; w < 4; ++w) {
      const float yb = __fadd_rn(__fmul_rn(y[w][t], sc), bi);
      v[w] = __fadd_rn(v[w], __fmul_rn(__fsub_rn(yb, v[w]), 0.5f));
      const bool fire = (v[w] >= 1.0f);
      if (fire) v[w] = 0.f;
      const u64 bl = __ballot(fire && act[w]);
      if (lane == 0) mb[(size_t)t * (D_ * 4) + w] = bl;
    }
  }
}

// ---------------------------------------------------------------------------
// k_attn: per (h,b): masks to LDS, build qT + G bit-planes, apply
// out = sum_p 2^p popcount(qT & Gp[p][d]), attn-LIF, write binary spikes.
// Phase B reads Gp as ulonglong2 (b128, wave-uniform broadcast): 48
// issues/t/thread instead of 96.
// ---------------------------------------------------------------------------
__global__ __launch_bounds__(1024) void k_attn(
    const u64* __restrict__ MSK, float* __restrict__ O)
{
  const int h = blockIdx.x;   // 8
  const int b = blockIdx.y;   // 32
  __shared__ u64 msk[3][T_][D_][4];   // 18432 B
  __shared__ u64 qT[T_][208];         // 6656 B
  __shared__ u64 Gp[T_][8][D_];       // 12288 B (rows 384B -> 16B aligned)
  const int tid = threadIdx.x;
  const int wave = tid >> 6, lane = tid & 63;

  {
    const u64* ms = MSK + (size_t)(h * 32 + b) * 2304;
    u64* mf = &msk[0][0][0][0];
    for (int off = tid; off < 2304; off += 1024) mf[off] = ms[off];
  }
  __syncthreads();

  // qT[t][n] = q bits over j
  {
    const int t = wave >> 2, w = wave & 3;
    const int n = w * 64 + lane;
    u64 qr = 0ull;
#pragma unroll 8
    for (int j = 0; j < D_; ++j)
      qr |= ((msk[0][t][j][w] >> lane) & 1ull) << j;
    if (n < N_) qT[t][n] = qr;
  }
  // Gp[t][p][d]: bit-planes of G[j][d] = popcount_m(k_j & v_d), lanes=j
  for (int task = wave; task < T_ * D_; task += 16) {
    const int t = task / D_, d = task - (task / D_) * D_;
    const bool ja = (lane < D_);
    const int j = ja ? lane : (D_ - 1);
    const u64* kj = msk[1][t][j];
    const u64* vd = msk[2][t][d];
    const int gi = __popcll(kj[0] & vd[0]) + __popcll(kj[1] & vd[1]) +
                   __popcll(kj[2] & vd[2]) + __popcll(kj[3] & vd[3]);
#pragma unroll
    for (int p = 0; p < 8; ++p) {
      const u64 bl = __ballot(ja && ((gi >> p) & 1));
      if (lane == 0) Gp[t][p][d] = bl;
    }
  }
  __syncthreads();

  const int u = tid;
  if (u < 4 * N_) {
    const int dq = u / N_;
    const int n = u - dq * N_;
    const int d0 = dq * 12;                    // 96B-aligned into Gp row
    float vmem[12];
#pragma unroll
    for (int i = 0; i < 12; ++i) vmem[i] = 0.f;
    for (int t = 0; t < T_; ++t) {
      const u64 qr = qT[t][n];
      int acc[12];
#pragma unroll
      for (int i = 0; i < 12; ++i) acc[i] = 0;
#pragma unroll
      for (int p = 0; p < 8; ++p) {
        const ulonglong2* gp = (const ulonglong2*)&Gp[t][p][d0];
#pragma unroll
        for (int ii = 0; ii < 6; ++ii) {       // 6 x b128 (wave-uniform)
          const ulonglong2 gv = gp[ii];
          acc[2 * ii + 0] += __popcll(qr & gv.x) << p;
          acc[2 * ii + 1] += __popcll(qr & gv.y) << p;
        }
      }
      float* ob = O + ((size_t)(t * B_ + b) * C_ + h * D_ + d0) * N_ + n;
#pragma unroll
      for (int i = 0; i < 12; ++i) {
        const float y = __int2float_rn(acc[i]) * 0.125f;  // exact
        vmem[i] = __fadd_rn(vmem[i], __fmul_rn(__fsub_rn(y, vmem[i]), 0.5f));
        const bool fire = (vmem[i] >= 0.5f);
        ob[(size_t)i * N_] = fire ? 1.0f : 0.0f;
        if (fire) vmem[i] = 0.f;
      }
    }
  }
}

// ---------------------------------------------------------------------------
extern "C" void kernel_launch(void* const* d_in, const int* in_sizes, int n_in,
                              void* d_out, int out_size, void* d_ws, size_t ws_size,
                              hipStream_t stream) {
  const float* x  = (const float*)d_in[0];
  const float* wq = (const float*)d_in[1];
  const float* sq = (const float*)d_in[2];
  const float* bq = (const float*)d_in[3];
  const float* wk = (const float*)d_in[4];
  const float* sk = (const float*)d_in[5];
  const float* bk = (const float*)d_in[6];
  const float* wv = (const float*)d_in[7];
  const float* sv = (const float*)d_in[8];
  const float* bv = (const float*)d_in[9];
  const float* wp = (const float*)d_in[10];
  const float* sp = (const float*)d_in[11];
  const float* bp = (const float*)d_in[12];
  float* out = (float*)d_out;

  float* P = (float*)d_ws;              // 3*TBCN qkv preacts
  float* O = P + 3 * TBCN_;             // TBCN attn spikes
  u64* MSK = (u64*)(P + 4 * TBCN_);     // 256 * 2304 u64 = 4.7 MB
  float* P2 = P;                        // final conv preact reuses q region

  gemm_f32<<<dim3(196, 3, 3), 256, 0, stream>>>(x, wq, wk, wv, P);
  k_mask<<<dim3(9216), 256, 0, stream>>>(P, MSK, sq, bq, sk, bk, sv, bv);
  k_attn<<<dim3(NH_, B_), 1024, 0, stream>>>(MSK, O);
  gemm_f32<<<dim3(196, 3, 1), 256, 0, stream>>>(O, wp, wp, wp, P2);
  lif4<<<dim3((BCN4_ + 255) / 256), 256, 0, stream>>>(P2, out, sp, bp, 1.0f);
}

// Round 13
// 503.231 us; speedup vs baseline: 1.3207x; 1.1711x over previous
//
#include <hip/hip_runtime.h>

// Spiking self-attention block (spikformer SSA), MI355X fp32 implementation.
// T=4 B=32 C=384 H=W=14 (N=196), heads=8, d=48.
//
// Exactness: LIF spikes are EXACTLY 0/1; attention is exact integer math.
// Conv GEMM: single fp32 accumulator per output, ascending K, fmaf per step
// (matched XLA bit-for-bit rounds 1-12). MFMA off the table (order change).
//
// R13: assembly of best-measured pieces + ONE variable:
// - GEMM = R9 verbatim (BK=16 + register prefetch, 258 us) EXCEPT
//   __launch_bounds__(256) SINGLE-ARG. R9's (256,2) showed occupancy 28%
//   = exactly 2 blocks/CU despite VGPR=68 (7 waves/SIMD possible) and
//   16 KB LDS (10 blocks possible) -> hypothesis: the 2nd arg maps to
//   amdgpu-waves-per-eu=(2,2), i.e. a MAX, self-capping residency. With
//   the cap removed, 5-7 blocks/CU should hide the staging stalls.
// - k_mask / k_attn / lif4 = R8 verbatim (best-measured chain; R9's
//   tweaks cost ~25 us, R12's b128 variant unproven).
// BK=32 (R12) is dead: 292 MB WRITE_SIZE = scratch spill, 321 us.

#define T_ 4
#define B_ 32
#define C_ 384
#define N_ 196
#define NH_ 8
#define D_ 48
#define TB_ (T_ * B_)                 // 128
#define CN_ ((size_t)C_ * N_)         // 75264
#define BCN4_ (B_ * C_ * (N_ / 4))    // 602112 float4 units per (g,t)
#define TBCN_ ((size_t)T_ * B_ * C_ * N_)  // 9,633,792 floats
typedef unsigned long long u64;

// ---------------------------------------------------------------------------
// GEMM (R9 + single-arg bounds): Y[g][tb][co][n] = sum_c W[co][c]*X[tb][c][n]
// Cols flattened j = tb*196 + n; 25088 = 196 tiles of 128 (exact).
// Block: 128co x 128col, 256 thr, 8x8/thread in two stride-64 quads.
// grid: x = col-tile (196), y = co-tile (3), z = g
// ---------------------------------------------------------------------------
__global__ __launch_bounds__(256) void gemm_f32(
    const float* __restrict__ X, const float* __restrict__ W0,
    const float* __restrict__ W1, const float* __restrict__ W2,
    float* __restrict__ P)
{
  const int g = blockIdx.z;
  const float* __restrict__ W = (g == 0) ? W0 : (g == 1) ? W1 : W2;
  const int co0 = blockIdx.y * 128;
  const int j0 = blockIdx.x * 128;
  __shared__ float As[16][128];
  __shared__ float Bs[16][128];
  const int tid = threadIdx.x;
  const int tx = tid & 15, ty = tid >> 4;

  const int bcol = (tid & 31) * 4;
  const int bk = tid >> 5;
  const int bj = j0 + bcol;
  const int btb = bj / N_;
  const float* xb = X + (size_t)btb * CN_ + (bj - btb * N_);
  const int arow = tid >> 1;
  const int ac8 = (tid & 1) * 8;
  const float* wrow0 = W + (size_t)(co0 + arow) * C_ + ac8;

  // Prefetch tile 0 into registers.
  float4 pa0 = *(const float4*)(wrow0);
  float4 pa1 = *(const float4*)(wrow0 + 4);
  float4 pb0 = *(const float4*)(xb + (size_t)bk * N_);
  float4 pb1 = *(const float4*)(xb + (size_t)(bk + 8) * N_);

  float acc[8][8] = {};
  for (int c0 = 0; c0 < C_; c0 += 16) {
    __syncthreads();   // prev-iter readers done (no-op on first iter)
    As[ac8 + 0][arow] = pa0.x; As[ac8 + 1][arow] = pa0.y;
    As[ac8 + 2][arow] = pa0.z; As[ac8 + 3][arow] = pa0.w;
    As[ac8 + 4][arow] = pa1.x; As[ac8 + 5][arow] = pa1.y;
    As[ac8 + 6][arow] = pa1.z; As[ac8 + 7][arow] = pa1.w;
    *(float4*)&Bs[bk][bcol] = pb0;
    *(float4*)&Bs[bk + 8][bcol] = pb1;
    __syncthreads();
    if (c0 + 16 < C_) {  // prefetch next tile; latency hidden by compute below
      pa0 = *(const float4*)(wrow0 + c0 + 16);
      pa1 = *(const float4*)(wrow0 + c0 + 20);
      pb0 = *(const float4*)(xb + (size_t)(c0 + 16 + bk) * N_);
      pb1 = *(const float4*)(xb + (size_t)(c0 + 24 + bk) * N_);
    }
#pragma unroll
    for (int k = 0; k < 16; ++k) {
      float a[8], b[8];
      *(float4*)&a[0] = *(const float4*)&As[k][ty * 4];
      *(float4*)&a[4] = *(const float4*)&As[k][64 + ty * 4];
      *(float4*)&b[0] = *(const float4*)&Bs[k][tx * 4];
      *(float4*)&b[4] = *(const float4*)&Bs[k][64 + tx * 4];
#pragma unroll
      for (int i = 0; i < 8; ++i)
#pragma unroll
        for (int j = 0; j < 8; ++j)
          acc[i][j] = fmaf(a[i], b[j], acc[i][j]);
    }
  }
#pragma unroll
  for (int cg = 0; cg < 2; ++cg) {
    const int jj = j0 + cg * 64 + tx * 4;
    const int tb = jj / N_;
    float* pb = P + (size_t)(g * TB_ + tb) * CN_ + (jj - tb * N_);
#pragma unroll
    for (int rg = 0; rg < 2; ++rg) {
#pragma unroll
      for (int i = 0; i < 4; ++i) {
        const int r = rg * 4 + i;
        const int co = co0 + rg * 64 + ty * 4 + i;
        *(float4*)&pb[(size_t)co * N_] = make_float4(
            acc[r][cg * 4 + 0], acc[r][cg * 4 + 1],
            acc[r][cg * 4 + 2], acc[r][cg * 4 + 3]);
      }
    }
  }
}

// ---------------------------------------------------------------------------
// Multi-step LIF over t with folded BN (final conv only).
// ---------------------------------------------------------------------------
__global__ __launch_bounds__(256) void lif4(
    const float* __restrict__ In, float* __restrict__ Out,
    const float* __restrict__ s0, const float* __restrict__ b0, float vth)
{
  const long u = (long)blockIdx.x * 256 + threadIdx.x;
  if (u >= BCN4_) return;
  const long r = u;
  const int c = (int)((r / (N_ / 4)) % C_);
  const bool has_bn = (s0 != nullptr);
  const float sc = has_bn ? s0[c] : 1.0f;
  const float bi = has_bn ? b0[c] : 0.0f;
  const float4* In4 = (const float4*)In;
  float4* Out4 = (float4*)Out;
  float v[4] = {0.f, 0.f, 0.f, 0.f};
#pragma unroll
  for (int t = 0; t < T_; ++t) {
    const long idx = (long)t * BCN4_ + r;
    const float4 y4 = In4[idx];
    float y[4] = {y4.x, y4.y, y4.z, y4.w};
    float o[4];
#pragma unroll
    for (int e = 0; e < 4; ++e) {
      const float yb = has_bn ? __fadd_rn(__fmul_rn(y[e], sc), bi) : y[e];
      v[e] = __fadd_rn(v[e], __fmul_rn(__fsub_rn(yb, v[e]), 0.5f));
      const bool fire = (v[e] >= vth);
      o[e] = fire ? 1.0f : 0.0f;
      v[e] = fire ? 0.0f : v[e];
    }
    Out4[idx] = make_float4(o[0], o[1], o[2], o[3]);
  }
}

// ---------------------------------------------------------------------------
// k_mask (R8): conv-LIF -> spike bitmasks. Wave-task = (g,h,b,j): 16 loads
// in flight, LIF recurrence, 16 ballots, lane0 stores 16 u64.
// MSK layout: [(h*32+b)][g][t][j][w]  (2304 u64 per (h,b)).
// ---------------------------------------------------------------------------
__global__ __launch_bounds__(256) void k_mask(
    const float* __restrict__ P, u64* __restrict__ MSK,
    const float* __restrict__ sq, const float* __restrict__ bq,
    const float* __restrict__ sk, const float* __restrict__ bk,
    const float* __restrict__ sv, const float* __restrict__ bv)
{
  const int wave = threadIdx.x >> 6, lane = threadIdx.x & 63;
  const int task = blockIdx.x * 4 + wave;      // 0..36863
  const int j = task % D_;
  int r = task / D_;
  const int b = r & 31; r >>= 5;
  const int h = r & 7;  r >>= 3;
  const int g = r;                              // 0..2
  const int c = h * D_ + j;
  const float sc = (g == 0 ? sq : g == 1 ? sk : sv)[c];
  const float bi = (g == 0 ? bq : g == 1 ? bk : bv)[c];
  const float* base = P + (size_t)g * TB_ * CN_ + (size_t)b * CN_ + (size_t)c * N_;

  float y[4][T_];
  bool act[4];
#pragma unroll
  for (int w = 0; w < 4; ++w) {
    const int m = w * 64 + lane;
    act[w] = (m < N_);
    const int mc = act[w] ? m : (N_ - 1);
#pragma unroll
    for (int t = 0; t < T_; ++t)
      y[w][t] = base[(size_t)t * B_ * CN_ + mc];   // 16 independent loads
  }
  u64* mb = MSK + ((size_t)(h * 32 + b) * 3 + g) * (T_ * D_ * 4) + j * 4;
  float v[4] = {0.f, 0.f, 0.f, 0.f};
#pragma unroll
  for (int t = 0; t < T_; ++t) {
#pragma unroll
    for (int w = 0; w < 4; ++w) {
      const float yb = __fadd_rn(__fmul_rn(y[w][t], sc), bi);
      v[w] = __fadd_rn(v[w], __fmul_rn(__fsub_rn(yb, v[w]), 0.5f));
      const bool fire = (v[w] >= 1.0f);
      if (fire) v[w] = 0.f;
      const u64 bl = __ballot(fire && act[w]);
      if (lane == 0) mb[(size_t)t * (D_ * 4) + w] = bl;
    }
  }
}

// ---------------------------------------------------------------------------
// k_attn (R8): per (h,b): masks to LDS, build qT + G bit-planes, apply
// out = sum_p 2^p popcount(qT & Gp[p][d]), attn-LIF, write binary spikes.
// ---------------------------------------------------------------------------
__global__ __launch_bounds__(1024) void k_attn(
    const u64* __restrict__ MSK, float* __restrict__ O)
{
  const int h = blockIdx.x;   // 8
  const int b = blockIdx.y;   // 32
  __shared__ u64 msk[3][T_][D_][4];   // 18432 B
  __shared__ u64 qT[T_][208];         // 6656 B
  __shared__ u64 Gp[T_][8][D_];       // 12288 B
  const int tid = threadIdx.x;
  const int wave = tid >> 6, lane = tid & 63;

  {
    const u64* ms = MSK + (size_t)(h * 32 + b) * 2304;
    u64* mf = &msk[0][0][0][0];
    for (int off = tid; off < 2304; off += 1024) mf[off] = ms[off];
  }
  __syncthreads();

  // qT[t][n] = q bits over j
  {
    const int t = wave >> 2, w = wave & 3;
    const int n = w * 64 + lane;
    u64 qr = 0ull;
#pragma unroll 8
    for (int j = 0; j < D_; ++j)
      qr |= ((msk[0][t][j][w] >> lane) & 1ull) << j;
    if (n < N_) qT[t][n] = qr;
  }
  // Gp[t][p][d]: bit-planes of G[j][d] = popcount_m(k_j & v_d), lanes=j
  for (int task = wave; task < T_ * D_; task += 16) {
    const int t = task / D_, d = task - (task / D_) * D_;
    const bool ja = (lane < D_);
    const int j = ja ? lane : (D_ - 1);
    const u64* kj = msk[1][t][j];
    const u64* vd = msk[2][t][d];
    const int gi = __popcll(kj[0] & vd[0]) + __popcll(kj[1] & vd[1]) +
                   __popcll(kj[2] & vd[2]) + __popcll(kj[3] & vd[3]);
#pragma unroll
    for (int p = 0; p < 8; ++p) {
      const u64 bl = __ballot(ja && ((gi >> p) & 1));
      if (lane == 0) Gp[t][p][d] = bl;
    }
  }
  __syncthreads();

  const int u = tid;
  if (u < 4 * N_) {
    const int dq = u / N_;
    const int n = u - dq * N_;
    const int d0 = dq * 12;
    float vmem[12];
#pragma unroll
    for (int i = 0; i < 12; ++i) vmem[i] = 0.f;
    for (int t = 0; t < T_; ++t) {
      const u64 qr = qT[t][n];
      float* ob = O + ((size_t)(t * B_ + b) * C_ + h * D_ + d0) * N_ + n;
#pragma unroll
      for (int i = 0; i < 12; ++i) {
        int acc = 0;
#pragma unroll
        for (int p = 0; p < 8; ++p)
          acc += __popcll(qr & Gp[t][p][d0 + i]) << p;
        const float y = __int2float_rn(acc) * 0.125f;  // exact
        vmem[i] = __fadd_rn(vmem[i], __fmul_rn(__fsub_rn(y, vmem[i]), 0.5f));
        const bool fire = (vmem[i] >= 0.5f);
        ob[(size_t)i * N_] = fire ? 1.0f : 0.0f;
        if (fire) vmem[i] = 0.f;
      }
    }
  }
}

// ---------------------------------------------------------------------------
extern "C" void kernel_launch(void* const* d_in, const int* in_sizes, int n_in,
                              void* d_out, int out_size, void* d_ws, size_t ws_size,
                              hipStream_t stream) {
  const float* x  = (const float*)d_in[0];
  const float* wq = (const float*)d_in[1];
  const float* sq = (const float*)d_in[2];
  const float* bq = (const float*)d_in[3];
  const float* wk = (const float*)d_in[4];
  const float* sk = (const float*)d_in[5];
  const float* bk = (const float*)d_in[6];
  const float* wv = (const float*)d_in[7];
  const float* sv = (const float*)d_in[8];
  const float* bv = (const float*)d_in[9];
  const float* wp = (const float*)d_in[10];
  const float* sp = (const float*)d_in[11];
  const float* bp = (const float*)d_in[12];
  float* out = (float*)d_out;

  float* P = (float*)d_ws;              // 3*TBCN qkv preacts
  float* O = P + 3 * TBCN_;             // TBCN attn spikes
  u64* MSK = (u64*)(P + 4 * TBCN_);     // 256 * 2304 u64 = 4.7 MB
  float* P2 = P;                        // final conv preact reuses q region

  gemm_f32<<<dim3(196, 3, 3), 256, 0, stream>>>(x, wq, wk, wv, P);
  k_mask<<<dim3(9216), 256, 0, stream>>>(P, MSK, sq, bq, sk, bk, sv, bv);
  k_attn<<<dim3(NH_, B_), 1024, 0, stream>>>(MSK, O);
  gemm_f32<<<dim3(196, 3, 1), 256, 0, stream>>>(O, wp, wp, wp, P2);
  lif4<<<dim3((BCN4_ + 255) / 256), 256, 0, stream>>>(P2, out, sp, bp, 1.0f);
}